// Round 4
// baseline (470.178 us; speedup 1.0000x reference)
//
#include <hip/hip_runtime.h>
#include <hip/hip_bf16.h>
#include <cstddef>

#define BB 1024
#define TT 4096
#define LL 30
#define HH 32
// P = 2, DT = 1.0

typedef int v2i __attribute__((ext_vector_type(2)));

// ---- fast branch-free tanh (encoder + epilogue): abs err ~1e-7 ----
__device__ __forceinline__ float tanh_fast(float x) {
    float t = __builtin_amdgcn_exp2f(x * 2.8853900817779268f);
    float r = __builtin_amdgcn_rcpf(t + 1.0f);
    return fmaf(-2.0f, r, 1.0f);
}

// ---- DPP add step (within-16-lane rows) ----
template <int CTRL>
__device__ __forceinline__ float dpp_add_f(float x) {
    int yi = __builtin_amdgcn_update_dpp(0, __float_as_int(x), CTRL, 0xF, 0xF, true);
    return x + __int_as_float(yi);
}

// Layout B3: unit j = (lane&15) + 16*(lane>>5); chain c = (lane>>4)&1.
// Chain c occupies rows {c, c+2} (its two 16-lane rows are lane^32 apart).
// Reduce q0,q1 over each chain's 32 lanes; both sums broadcast to ALL lanes.
// swap(q0,q1): dst={q0.rows01,q1.rows01}, src={q0.rows23,q1.rows23};
// C=dst+src -> C.lo = q0 cross-row pairs, C.hi = q1 cross-row pairs.
// 4-level DPP tree within rows -> row0=S0c0,row1=S0c1,row2=S1c0,row3=S1c1.
// swap(C,C): dst = rows01 replicated (S0 for own chain, all lanes),
//            src = rows23 replicated (S1 for own chain, all lanes).
__device__ __forceinline__ void chain_reduce(float q0, float q1, float& S0, float& S1) {
    v2i sw = __builtin_amdgcn_permlane32_swap(__float_as_int(q0), __float_as_int(q1), false, false);
    float C = __int_as_float(sw.x) + __int_as_float(sw.y);
    C = dpp_add_f<0xB1>(C);    // xor1
    C = dpp_add_f<0x4E>(C);    // xor2
    C = dpp_add_f<0x141>(C);   // row_half_mirror
    C = dpp_add_f<0x140>(C);   // row_mirror
    v2i pq = __builtin_amdgcn_permlane32_swap(__float_as_int(C), __float_as_int(C), false, false);
    S0 = __int_as_float(pq.x);
    S1 = __int_as_float(pq.y);
}

// Two independent reductions, statement-interleaved to fill latency shadows.
__device__ __forceinline__ void chain_reduce2(float qA0, float qA1, float qB0, float qB1,
                                              float& SA0, float& SA1, float& SB0, float& SB1) {
    v2i swA = __builtin_amdgcn_permlane32_swap(__float_as_int(qA0), __float_as_int(qA1), false, false);
    v2i swB = __builtin_amdgcn_permlane32_swap(__float_as_int(qB0), __float_as_int(qB1), false, false);
    float CA = __int_as_float(swA.x) + __int_as_float(swA.y);
    float CB = __int_as_float(swB.x) + __int_as_float(swB.y);
    CA = dpp_add_f<0xB1>(CA);   CB = dpp_add_f<0xB1>(CB);
    CA = dpp_add_f<0x4E>(CA);   CB = dpp_add_f<0x4E>(CB);
    CA = dpp_add_f<0x141>(CA);  CB = dpp_add_f<0x141>(CB);
    CA = dpp_add_f<0x140>(CA);  CB = dpp_add_f<0x140>(CB);
    v2i pqA = __builtin_amdgcn_permlane32_swap(__float_as_int(CA), __float_as_int(CA), false, false);
    v2i pqB = __builtin_amdgcn_permlane32_swap(__float_as_int(CB), __float_as_int(CB), false, false);
    SA0 = __int_as_float(pqA.x);  SA1 = __int_as_float(pqA.y);
    SB0 = __int_as_float(pqB.x);  SB1 = __int_as_float(pqB.y);
}

// Kernel 1: encoder + sequential Euler scan.
// 32 lanes per chain (1 hidden unit/lane -> 2 trans ops/step instead of 4),
// 2 chains per register-set, 2 sets per wave (4 chains/wave, 256 waves, 1/CU).
// Burst-16 history capture via branch-free selects, coalesced stores.
__global__ __launch_bounds__(64) void ode_scan_kernel(
    const float* __restrict__ x,
    const float* __restrict__ ew1, const float* __restrict__ eb1,
    const float* __restrict__ ew2, const float* __restrict__ eb2,
    const float* __restrict__ fw1, const float* __restrict__ fb1,
    const float* __restrict__ fw2, const float* __restrict__ fb2,
    float* __restrict__ zout)
{
    const int tid = threadIdx.x;
    const int g   = tid & 15;                     // position within row
    const int c   = (tid >> 4) & 1;               // chain within set
    const int j   = g + ((tid >> 5) << 4);        // hidden unit (0..31)

    const int bA = blockIdx.x * 4 + c;            // set A chain
    const int bB = bA + 2;                        // set B chain

    // ---- f-MLP weights, prescaled/folded ----
    const float KE  = 2.8853900817779268f;        // 2*log2(e)
    const float w1  = fw1[j] * KE;
    const float w1b = fw1[HH + j] * KE;
    const float b1  = fb1[j] * KE;
    const float w20 = fw2[j * 2 + 0], w21 = fw2[j * 2 + 1];
    const float n0  = -2.0f * w20,    n1  = -2.0f * w21;
    const float base0 = w20 + fb2[0] * (1.0f / 32.0f);  // red over 32 lanes now
    const float base1 = w21 + fb2[1] * (1.0f / 32.0f);

    // ---------------- encoder for both sets
    float zA1, zA2, zB1, zB2;
    {
        float sA = eb1[j], sB = eb1[j];
        const float* xa = x + (size_t)bA * TT;
        const float* xb = x + (size_t)bB * TT;
        #pragma unroll
        for (int l = 0; l < LL; ++l) {
            float w = ew1[l * HH + j];
            sA = fmaf(xa[l], w, sA);
            sB = fmaf(xb[l], w, sB);
        }
        float hA = tanh_fast(sA), hB = tanh_fast(sB);
        float e20 = ew2[j * 2 + 0], e21 = ew2[j * 2 + 1];
        float SA0, SA1, SB0, SB1;
        chain_reduce2(hA * e20, hA * e21, hB * e20, hB * e21, SA0, SA1, SB0, SB1);
        zA1 = SA0 + eb2[0];  zA2 = SA1 + eb2[1];
        zB1 = SB0 + eb2[0];  zB2 = SB1 + eb2[1];
    }

    // one Euler superstep: both sets interleaved (DT=1, b2 folded into base)
    #define STEP2() do {                                         \
        float aA = fmaf(zA2, w1b, fmaf(zA1, w1, b1));            \
        float aB = fmaf(zB2, w1b, fmaf(zB1, w1, b1));            \
        float eA = __builtin_amdgcn_exp2f(aA);                   \
        float eB = __builtin_amdgcn_exp2f(aB);                   \
        float tA = eA + 1.0f;                                    \
        float tB = eB + 1.0f;                                    \
        float rA = __builtin_amdgcn_rcpf(tA);                    \
        float rB = __builtin_amdgcn_rcpf(tB);                    \
        float qA0 = fmaf(rA, n0, base0);                         \
        float qA1 = fmaf(rA, n1, base1);                         \
        float qB0 = fmaf(rB, n0, base0);                         \
        float qB1 = fmaf(rB, n1, base1);                         \
        float SA0, SA1, SB0, SB1;                                \
        chain_reduce2(qA0, qA1, qB0, qB1, SA0, SA1, SB0, SB1);   \
        zA1 += SA0; zA2 += SA1;                                  \
        zB1 += SB0; zB2 += SB1;                                  \
    } while (0)

    #define CAPTURE(k) do {                                      \
        bool cp = (g == (k));                                    \
        hA1 = cp ? zA1 : hA1;  hA2 = cp ? zA2 : hA2;             \
        hB1 = cp ? zB1 : hB1;  hB2 = cp ? zB2 : hB2;             \
    } while (0)

    // history regs: within each burst of 16 steps, the lane with g==k holds
    // timeline entry k; rows 2,3 duplicate rows 0,1 (harmless, not stored).
    float hA1 = zA1, hA2 = zA2, hB1 = zB1, hB2 = zB2;
    float* zpA = zout + (size_t)bA * TT * 2 + g * 2;
    float* zpB = zout + (size_t)bB * TT * 2 + g * 2;
    const bool storer = (tid < 32);   // rows 0,1 hold chains 0,1 captures

    // ---- prologue burst: entries 1..15 (h init covers entry 0 at g==0)
    #pragma unroll
    for (int k = 1; k < 16; ++k) { STEP2(); CAPTURE(k); }
    if (storer) {
        float2 vA; vA.x = hA1; vA.y = hA2; *(float2*)zpA = vA;
        float2 vB; vB.x = hB1; vB.y = hB2; *(float2*)zpB = vB;
    }
    zpA += 32; zpB += 32;

    // ---- main loop: 255 bursts x 16 steps
    for (int bb = 1; bb < 256; ++bb) {
        #pragma unroll
        for (int k = 0; k < 16; ++k) { STEP2(); CAPTURE(k); }
        if (storer) {
            float2 vA; vA.x = hA1; vA.y = hA2; *(float2*)zpA = vA;
            float2 vB; vB.x = hB1; vB.y = hB2; *(float2*)zpB = vB;
        }
        zpA += 32; zpB += 32;
    }
    #undef STEP2
    #undef CAPTURE
}

// Kernel 2: streaming epilogue. Reads z (out2) + phi, writes a (out1) and xhat (out0).
__global__ __launch_bounds__(256) void finalize_kernel(
    const float* __restrict__ phi, const float* __restrict__ z,
    float* __restrict__ xhat, float* __restrict__ a)
{
    const int idx = blockIdx.x * blockDim.x + threadIdx.x;
    const int pos = idx * 2;                    // position pair (same b; t0 even)
    const int t0  = pos & (TT - 1);

    float4 zv = *(const float4*)(z   + (size_t)pos * 2);
    float4 pv = *(const float4*)(phi + (size_t)pos * 2);

    float k1a = tanh_fast(zv.x), k2a = tanh_fast(zv.y);
    float k1b = tanh_fast(zv.z), k2b = tanh_fast(zv.w);

    float a1a = k1a * (1.0f - k2a), a2a = k2a;
    float a1b = k1b * (1.0f - k2b), a2b = k2b;

    float4 av; av.x = a1a; av.y = a2a; av.z = a1b; av.w = a2b;
    *(float4*)(a + (size_t)pos * 2) = av;

    float x0 = (t0 >= 2)     ? fmaf(a2a, pv.y, a1a * pv.x) : 0.0f;
    float x1 = (t0 + 1 >= 2) ? fmaf(a2b, pv.w, a1b * pv.z) : 0.0f;
    float2 xv; xv.x = x0; xv.y = x1;
    *(float2*)(xhat + pos) = xv;
}

extern "C" void kernel_launch(void* const* d_in, const int* in_sizes, int n_in,
                              void* d_out, int out_size, void* d_ws, size_t ws_size,
                              hipStream_t stream) {
    const float* x    = (const float*)d_in[0];
    const float* phi  = (const float*)d_in[1];
    const float* ew1  = (const float*)d_in[2];
    const float* eb1  = (const float*)d_in[3];
    const float* ew2  = (const float*)d_in[4];
    const float* eb2  = (const float*)d_in[5];
    const float* fw1  = (const float*)d_in[6];
    const float* fb1  = (const float*)d_in[7];
    const float* fw2  = (const float*)d_in[8];
    const float* fb2  = (const float*)d_in[9];

    float* out  = (float*)d_out;
    float* xhat = out;                          // (B, T)
    float* a    = out + (size_t)BB * TT;        // (B, T, 2)
    float* z    = out + (size_t)BB * TT * 3;    // (B, T, 2)

    // 256 blocks x 64 threads: 1 wave/block, 1 block/CU, 4 chains/wave
    ode_scan_kernel<<<256, 64, 0, stream>>>(x, ew1, eb1, ew2, eb2,
                                            fw1, fb1, fw2, fb2, z);

    const int total_pairs = (BB * TT) / 2;
    finalize_kernel<<<total_pairs / 256, 256, 0, stream>>>(phi, z, xhat, a);
}

// Round 5
// 286.289 us; speedup vs baseline: 1.6423x; 1.6423x over previous
//
#include <hip/hip_runtime.h>
#include <hip/hip_bf16.h>
#include <cstddef>

#define BB 1024
#define TT 4096
#define LL 30
#define HH 32
// P = 2, DT = 1.0

typedef int v2i __attribute__((ext_vector_type(2)));

// ---- fast branch-free tanh (encoder + epilogue): abs err ~1e-7 ----
__device__ __forceinline__ float tanh_fast(float x) {
    float t = __builtin_amdgcn_exp2f(x * 2.8853900817779268f);
    float r = __builtin_amdgcn_rcpf(t + 1.0f);
    return fmaf(-2.0f, r, 1.0f);
}

// ---- DPP add step (within-16-lane rows) ----
template <int CTRL>
__device__ __forceinline__ float dpp_add_f(float x) {
    int yi = __builtin_amdgcn_update_dpp(0, __float_as_int(x), CTRL, 0xF, 0xF, true);
    return x + __int_as_float(yi);
}

// Layout B3 (correctness-proven in round 4): unit j = (lane&15) + 16*(lane>>5),
// chain c = (lane>>4)&1. Chain c occupies rows {c, c+2} (lane^32 apart).
// chain_reduce: sum q0,q1 over each chain's 32 lanes, broadcast both sums to
// all of that chain's lanes.
//   swap(q0,q1) -> sw.x={q0.r01,q1.r01}, sw.y={q0.r23,q1.r23};
//   C=sw.x+sw.y -> r0: chain0 q0-pairs, r1: chain1 q0-pairs,
//                  r2: chain0 q1-pairs, r3: chain1 q1-pairs.
//   4-level DPP tree within rows -> each row holds its 16-lane sum.
//   swap(C,C)   -> pq.x = own-chain S0 in every lane, pq.y = own-chain S1.
__device__ __forceinline__ void chain_reduce(float q0, float q1, float& S0, float& S1) {
    v2i sw = __builtin_amdgcn_permlane32_swap(__float_as_int(q0), __float_as_int(q1), false, false);
    float C = __int_as_float(sw.x) + __int_as_float(sw.y);
    C = dpp_add_f<0xB1>(C);    // quad_perm xor1
    C = dpp_add_f<0x4E>(C);    // quad_perm xor2
    C = dpp_add_f<0x141>(C);   // row_half_mirror
    C = dpp_add_f<0x140>(C);   // row_mirror
    v2i pq = __builtin_amdgcn_permlane32_swap(__float_as_int(C), __float_as_int(C), false, false);
    S0 = __int_as_float(pq.x);
    S1 = __int_as_float(pq.y);
}

// Kernel 1: encoder + sequential Euler scan.
// 32 lanes per chain (1 hidden unit/lane -> only 2 trans ops/step),
// 2 chains per wave, 512 waves (2 per CU). Burst-16 history capture via
// branch-free selects, one coalesced 128B store per chain per 16 steps.
__global__ __launch_bounds__(64) void ode_scan_kernel(
    const float* __restrict__ x,
    const float* __restrict__ ew1, const float* __restrict__ eb1,
    const float* __restrict__ ew2, const float* __restrict__ eb2,
    const float* __restrict__ fw1, const float* __restrict__ fb1,
    const float* __restrict__ fw2, const float* __restrict__ fb2,
    float* __restrict__ zout)
{
    const int tid = threadIdx.x;
    const int g   = tid & 15;                     // position within row
    const int c   = (tid >> 4) & 1;               // chain within wave
    const int j   = g + ((tid >> 5) << 4);        // hidden unit (0..31)
    const int b   = blockIdx.x * 2 + c;           // batch chain

    // ---- f-MLP weights, prescaled/folded ----
    const float KE  = 2.8853900817779268f;        // 2*log2(e)
    const float w1  = fw1[j] * KE;
    const float w1b = fw1[HH + j] * KE;
    const float b1  = fb1[j] * KE;
    const float w20 = fw2[j * 2 + 0], w21 = fw2[j * 2 + 1];
    const float n0  = -2.0f * w20,    n1  = -2.0f * w21;
    const float base0 = w20 + fb2[0] * (1.0f / 32.0f);  // reduce spans 32 lanes
    const float base1 = w21 + fb2[1] * (1.0f / 32.0f);

    // ---------------- encoder: z0 = tanh(x[:, :30] @ ew1 + eb1) @ ew2 + eb2
    float z1, z2;
    {
        float s = eb1[j];
        const float* xb = x + (size_t)b * TT;
        #pragma unroll
        for (int l = 0; l < LL; ++l)
            s = fmaf(xb[l], ew1[l * HH + j], s);
        float h = tanh_fast(s);
        float S0, S1;
        chain_reduce(h * ew2[j * 2 + 0], h * ew2[j * 2 + 1], S0, S1);
        z1 = S0 + eb2[0];
        z2 = S1 + eb2[1];
    }

    // one Euler step (DT=1, b2 folded into base via the 32-lane reduction)
    #define STEP() do {                                          \
        float aa = fmaf(z2, w1b, fmaf(z1, w1, b1));              \
        float ee = __builtin_amdgcn_exp2f(aa);                   \
        float rr = __builtin_amdgcn_rcpf(ee + 1.0f);             \
        float q0 = fmaf(rr, n0, base0);                          \
        float q1 = fmaf(rr, n1, base1);                          \
        float S0, S1;                                            \
        chain_reduce(q0, q1, S0, S1);                            \
        z1 += S0; z2 += S1;                                      \
    } while (0)

    #define CAPTURE(k) do {                                      \
        bool cp = (g == (k));                                    \
        h1 = cp ? z1 : h1;                                       \
        h2 = cp ? z2 : h2;                                       \
    } while (0)

    // history regs: lane with g==k holds timeline entry (16*burst + k) of its
    // own chain; rows 2,3 duplicate rows 0,1 (not stored).
    float h1 = z1, h2 = z2;
    float* zp = zout + (size_t)b * TT * 2 + g * 2;
    const bool storer = (tid < 32);   // row0 -> chain0, row1 -> chain1

    // ---- prologue burst: entries 1..15 (h init covers entry 0 at g==0)
    #pragma unroll
    for (int k = 1; k < 16; ++k) { STEP(); CAPTURE(k); }
    if (storer) { float2 v; v.x = h1; v.y = h2; *(float2*)zp = v; }
    zp += 32;

    // ---- main loop: 255 bursts x 16 steps
    for (int bb = 1; bb < 256; ++bb) {
        #pragma unroll
        for (int k = 0; k < 16; ++k) { STEP(); CAPTURE(k); }
        if (storer) { float2 v; v.x = h1; v.y = h2; *(float2*)zp = v; }
        zp += 32;
    }
    #undef STEP
    #undef CAPTURE
}

// Kernel 2: streaming epilogue. Reads z (out2) + phi, writes a (out1) and xhat (out0).
__global__ __launch_bounds__(256) void finalize_kernel(
    const float* __restrict__ phi, const float* __restrict__ z,
    float* __restrict__ xhat, float* __restrict__ a)
{
    const int idx = blockIdx.x * blockDim.x + threadIdx.x;
    const int pos = idx * 2;                    // position pair (same b; t0 even)
    const int t0  = pos & (TT - 1);

    float4 zv = *(const float4*)(z   + (size_t)pos * 2);
    float4 pv = *(const float4*)(phi + (size_t)pos * 2);

    float k1a = tanh_fast(zv.x), k2a = tanh_fast(zv.y);
    float k1b = tanh_fast(zv.z), k2b = tanh_fast(zv.w);

    float a1a = k1a * (1.0f - k2a), a2a = k2a;
    float a1b = k1b * (1.0f - k2b), a2b = k2b;

    float4 av; av.x = a1a; av.y = a2a; av.z = a1b; av.w = a2b;
    *(float4*)(a + (size_t)pos * 2) = av;

    float x0 = (t0 >= 2)     ? fmaf(a2a, pv.y, a1a * pv.x) : 0.0f;
    float x1 = (t0 + 1 >= 2) ? fmaf(a2b, pv.w, a1b * pv.z) : 0.0f;
    float2 xv; xv.x = x0; xv.y = x1;
    *(float2*)(xhat + pos) = xv;
}

extern "C" void kernel_launch(void* const* d_in, const int* in_sizes, int n_in,
                              void* d_out, int out_size, void* d_ws, size_t ws_size,
                              hipStream_t stream) {
    const float* x    = (const float*)d_in[0];
    const float* phi  = (const float*)d_in[1];
    const float* ew1  = (const float*)d_in[2];
    const float* eb1  = (const float*)d_in[3];
    const float* ew2  = (const float*)d_in[4];
    const float* eb2  = (const float*)d_in[5];
    const float* fw1  = (const float*)d_in[6];
    const float* fb1  = (const float*)d_in[7];
    const float* fw2  = (const float*)d_in[8];
    const float* fb2  = (const float*)d_in[9];

    float* out  = (float*)d_out;
    float* xhat = out;                          // (B, T)
    float* a    = out + (size_t)BB * TT;        // (B, T, 2)
    float* z    = out + (size_t)BB * TT * 3;    // (B, T, 2)

    // 512 blocks x 64 threads: 1 wave/block, 2 blocks/CU, 2 chains/wave
    ode_scan_kernel<<<512, 64, 0, stream>>>(x, ew1, eb1, ew2, eb2,
                                            fw1, fb1, fw2, fb2, z);

    const int total_pairs = (BB * TT) / 2;
    finalize_kernel<<<total_pairs / 256, 256, 0, stream>>>(phi, z, xhat, a);
}

// Round 6
// 275.222 us; speedup vs baseline: 1.7084x; 1.0402x over previous
//
#include <hip/hip_runtime.h>
#include <hip/hip_bf16.h>
#include <cstddef>

#define BB 1024
#define TT 4096
#define LL 30
#define HH 32
// P = 2, DT = 1.0

typedef int v2i __attribute__((ext_vector_type(2)));

// ---- fast branch-free tanh (encoder + epilogue): abs err ~1e-7 ----
__device__ __forceinline__ float tanh_fast(float x) {
    float t = __builtin_amdgcn_exp2f(x * 2.8853900817779268f);
    float r = __builtin_amdgcn_rcpf(t + 1.0f);
    return fmaf(-2.0f, r, 1.0f);
}

// ---- DPP add step (within-16-lane rows) ----
template <int CTRL>
__device__ __forceinline__ float dpp_add_f(float x) {
    int yi = __builtin_amdgcn_update_dpp(0, __float_as_int(x), CTRL, 0xF, 0xF, true);
    return x + __int_as_float(yi);
}

// Layout B3 (correctness-proven R4/R5): unit j = (lane&15) + 16*(lane>>5),
// chain c = (lane>>4)&1. Chain c occupies rows {c, c+2} (lane^32 apart).
// chain_reduce: sum q0,q1 over each chain's 32 lanes, broadcast both sums to
// all of that chain's lanes.
__device__ __forceinline__ void chain_reduce(float q0, float q1, float& S0, float& S1) {
    v2i sw = __builtin_amdgcn_permlane32_swap(__float_as_int(q0), __float_as_int(q1), false, false);
    float C = __int_as_float(sw.x) + __int_as_float(sw.y);
    C = dpp_add_f<0xB1>(C);    // quad_perm xor1
    C = dpp_add_f<0x4E>(C);    // quad_perm xor2
    C = dpp_add_f<0x141>(C);   // row_half_mirror
    C = dpp_add_f<0x140>(C);   // row_mirror
    v2i pq = __builtin_amdgcn_permlane32_swap(__float_as_int(C), __float_as_int(C), false, false);
    S0 = __int_as_float(pq.x);
    S1 = __int_as_float(pq.y);
}

// Kernel 1: encoder + sequential Euler scan.
// 32 lanes per chain (1 hidden unit/lane -> 2 trans ops/step), 2 chains/wave,
// 512 waves. Running-preactivation recurrence: aa[j] = w1[j]*z1 + w1b[j]*z2 + b1[j]
// is maintained incrementally (aa += w1*S0 + w1b*S1), so z updates and history
// capture are fully OFF the dependent chain. Burst-16 coalesced stores.
__global__ __launch_bounds__(64) void ode_scan_kernel(
    const float* __restrict__ x,
    const float* __restrict__ ew1, const float* __restrict__ eb1,
    const float* __restrict__ ew2, const float* __restrict__ eb2,
    const float* __restrict__ fw1, const float* __restrict__ fb1,
    const float* __restrict__ fw2, const float* __restrict__ fb2,
    float* __restrict__ zout)
{
    const int tid = threadIdx.x;
    const int g   = tid & 15;                     // position within row
    const int c   = (tid >> 4) & 1;               // chain within wave
    const int j   = g + ((tid >> 5) << 4);        // hidden unit (0..31)
    const int b   = blockIdx.x * 2 + c;           // batch chain

    // ---- f-MLP weights, prescaled/folded ----
    const float KE  = 2.8853900817779268f;        // 2*log2(e)
    const float w1  = fw1[j] * KE;
    const float w1b = fw1[HH + j] * KE;
    const float b1  = fb1[j] * KE;
    const float w20 = fw2[j * 2 + 0], w21 = fw2[j * 2 + 1];
    const float n0  = -2.0f * w20,    n1  = -2.0f * w21;
    const float base0 = w20 + fb2[0] * (1.0f / 32.0f);  // reduce spans 32 lanes
    const float base1 = w21 + fb2[1] * (1.0f / 32.0f);

    // ---------------- encoder: z0 = tanh(x[:, :30] @ ew1 + eb1) @ ew2 + eb2
    float z1, z2;
    {
        float s = eb1[j];
        const float* xb = x + (size_t)b * TT;
        #pragma unroll
        for (int l = 0; l < LL; ++l)
            s = fmaf(xb[l], ew1[l * HH + j], s);
        float h = tanh_fast(s);
        float S0, S1;
        chain_reduce(h * ew2[j * 2 + 0], h * ew2[j * 2 + 1], S0, S1);
        z1 = S0 + eb2[0];
        z2 = S1 + eb2[1];
    }

    // running first-layer preactivation for this lane's unit j
    float aa = fmaf(z2, w1b, fmaf(z1, w1, b1));

    // one Euler step. Chain: exp->add->rcp->fma->swap->add->dpp4->swap->fma->fma.
    // z updates + capture are off-chain (soak into latency stalls).
    #define STEP() do {                                          \
        float ee = __builtin_amdgcn_exp2f(aa);                   \
        float rr = __builtin_amdgcn_rcpf(ee + 1.0f);             \
        float q0 = fmaf(rr, n0, base0);                          \
        float q1 = fmaf(rr, n1, base1);                          \
        float S0, S1;                                            \
        chain_reduce(q0, q1, S0, S1);                            \
        aa = fmaf(S1, w1b, fmaf(S0, w1, aa));                    \
        z1 += S0; z2 += S1;                                      \
    } while (0)

    #define CAPTURE(k) do {                                      \
        bool cp = (g == (k));                                    \
        h1 = cp ? z1 : h1;                                       \
        h2 = cp ? z2 : h2;                                       \
    } while (0)

    // history regs: lane with g==k holds timeline entry (16*burst + k) of its
    // own chain; rows 2,3 duplicate rows 0,1 (not stored).
    float h1 = z1, h2 = z2;
    float* zp = zout + (size_t)b * TT * 2 + g * 2;
    const bool storer = (tid < 32);   // row0 -> chain0, row1 -> chain1

    // ---- prologue burst: entries 1..15 (h init covers entry 0 at g==0)
    #pragma unroll
    for (int k = 1; k < 16; ++k) { STEP(); CAPTURE(k); }
    if (storer) { float2 v; v.x = h1; v.y = h2; *(float2*)zp = v; }
    zp += 32;

    // ---- main loop: 255 bursts x 16 steps
    for (int bb = 1; bb < 256; ++bb) {
        #pragma unroll
        for (int k = 0; k < 16; ++k) { STEP(); CAPTURE(k); }
        if (storer) { float2 v; v.x = h1; v.y = h2; *(float2*)zp = v; }
        zp += 32;
    }
    #undef STEP
    #undef CAPTURE
}

// Kernel 2: streaming epilogue. Reads z (out2) + phi, writes a (out1) and xhat (out0).
__global__ __launch_bounds__(256) void finalize_kernel(
    const float* __restrict__ phi, const float* __restrict__ z,
    float* __restrict__ xhat, float* __restrict__ a)
{
    const int idx = blockIdx.x * blockDim.x + threadIdx.x;
    const int pos = idx * 2;                    // position pair (same b; t0 even)
    const int t0  = pos & (TT - 1);

    float4 zv = *(const float4*)(z   + (size_t)pos * 2);
    float4 pv = *(const float4*)(phi + (size_t)pos * 2);

    float k1a = tanh_fast(zv.x), k2a = tanh_fast(zv.y);
    float k1b = tanh_fast(zv.z), k2b = tanh_fast(zv.w);

    float a1a = k1a * (1.0f - k2a), a2a = k2a;
    float a1b = k1b * (1.0f - k2b), a2b = k2b;

    float4 av; av.x = a1a; av.y = a2a; av.z = a1b; av.w = a2b;
    *(float4*)(a + (size_t)pos * 2) = av;

    float x0 = (t0 >= 2)     ? fmaf(a2a, pv.y, a1a * pv.x) : 0.0f;
    float x1 = (t0 + 1 >= 2) ? fmaf(a2b, pv.w, a1b * pv.z) : 0.0f;
    float2 xv; xv.x = x0; xv.y = x1;
    *(float2*)(xhat + pos) = xv;
}

extern "C" void kernel_launch(void* const* d_in, const int* in_sizes, int n_in,
                              void* d_out, int out_size, void* d_ws, size_t ws_size,
                              hipStream_t stream) {
    const float* x    = (const float*)d_in[0];
    const float* phi  = (const float*)d_in[1];
    const float* ew1  = (const float*)d_in[2];
    const float* eb1  = (const float*)d_in[3];
    const float* ew2  = (const float*)d_in[4];
    const float* eb2  = (const float*)d_in[5];
    const float* fw1  = (const float*)d_in[6];
    const float* fb1  = (const float*)d_in[7];
    const float* fw2  = (const float*)d_in[8];
    const float* fb2  = (const float*)d_in[9];

    float* out  = (float*)d_out;
    float* xhat = out;                          // (B, T)
    float* a    = out + (size_t)BB * TT;        // (B, T, 2)
    float* z    = out + (size_t)BB * TT * 3;    // (B, T, 2)

    // 512 blocks x 64 threads: 1 wave/block, 2 chains/wave
    ode_scan_kernel<<<512, 64, 0, stream>>>(x, ew1, eb1, ew2, eb2,
                                            fw1, fb1, fw2, fb2, z);

    const int total_pairs = (BB * TT) / 2;
    finalize_kernel<<<total_pairs / 256, 256, 0, stream>>>(phi, z, xhat, a);
}